// Round 9
// baseline (912.149 us; speedup 1.0000x reference)
//
#include <hip/hip_runtime.h>
#include <hip/hip_bf16.h>
#include <cstdint>
#include <cstddef>

#define BTOK  8192
#define DIM   1024
#define NEXP  8
#define NHID  4096
#define HHALF 2048
#define GATE_TOK 64
#define ABASE (128 * 32)   // ushort offset of B region within one LDS buf

typedef __bf16 bf16x8 __attribute__((ext_vector_type(8)));
typedef float  floatx4 __attribute__((ext_vector_type(4)));

// ---- workspace layout (bytes) ----
#define O_COUNTS 0
#define O_BASE   256
#define O_TOKB   1024
#define O_TOKW   (O_TOKB + (size_t)NEXP*BTOK*4)
#define O_CE     (O_TOKW + (size_t)NEXP*BTOK*4)
#define O_CP     (O_CE + (size_t)2*BTOK*4)
#define O_CW     (O_CP + (size_t)2*BTOK*4)
#define O_ZBF    (O_CW + (size_t)2*BTOK*4)
#define O_W1T    (O_ZBF + (size_t)BTOK*DIM*2)
#define O_W2T    (O_W1T + (size_t)NEXP*DIM*NHID*2)
#define O_HBUF   (O_W2T + (size_t)NEXP*DIM*NHID*2)
#define WS_NEED  (O_HBUF + (size_t)2*BTOK*NHID*2)   // = 285,934,592 (proven available)

__device__ __forceinline__ void gload_lds16(const void* g, void* l) {
  __builtin_amdgcn_global_load_lds(
      (const __attribute__((address_space(1))) void*)g,
      (__attribute__((address_space(3))) void*)l, 16, 0, 0);
}

__device__ __forceinline__ ushort f2bf(float x) {
  return __builtin_bit_cast(ushort, __float2bfloat16(x));
}

// ---------------- zero counters + steal counters ----------------
__global__ void k_zcnt(int* __restrict__ counts) {
  if (threadIdx.x < 12) counts[threadIdx.x] = 0;
}

// ---------------- zero out (gemm2 accumulates atomically) ----------------
__global__ void k_zout(float* __restrict__ out) {
  int i = blockIdx.x * blockDim.x + threadIdx.x;
  float4 z4 = {0.f, 0.f, 0.f, 0.f};
  float4* o = (float4*)out;
  int n = BTOK * DIM / 4;
  for (int j = i; j < n; j += gridDim.x * blockDim.x) o[j] = z4;
}

// ---------------- transpose fp32 [Z][R][C] -> bf16 [Z][C][R] ----------------
__global__ __launch_bounds__(256) void k_transpose(
    const float* __restrict__ src, __hip_bfloat16* __restrict__ dst, int R, int C) {
  __shared__ float tile[32][33];
  int zz = blockIdx.z;
  const float* s = src + (size_t)zz * R * C;
  __hip_bfloat16* d = dst + (size_t)zz * R * C;
  int c0 = blockIdx.x * 32, r0 = blockIdx.y * 32;
  int tx = threadIdx.x & 31, ty = threadIdx.x >> 5;
#pragma unroll
  for (int i = ty; i < 32; i += 8)
    tile[i][tx] = s[(size_t)(r0 + i) * C + c0 + tx];
  __syncthreads();
#pragma unroll
  for (int i = ty; i < 32; i += 8)
    d[(size_t)(c0 + i) * R + r0 + tx] = __float2bfloat16(tile[tx][i]);
}

// ---------------- gating ----------------
__global__ __launch_bounds__(256) void k_gate(
    const float* __restrict__ z, const float* __restrict__ Wg,
    const float* __restrict__ bg, int* __restrict__ counts,
    int* __restrict__ tokb, float* __restrict__ tokw,
    __hip_bfloat16* __restrict__ zbf) {
  __shared__ float wgT[NEXP * DIM];       // [e][d]
  __shared__ int   le[2 * GATE_TOK];
  __shared__ float lw[2 * GATE_TOK];
  __shared__ int   lr[2 * GATE_TOK];
  __shared__ int   lcnt[NEXP];
  __shared__ int   gbase[NEXP];

  int tid = threadIdx.x;
  if (tid < NEXP) lcnt[tid] = 0;
#pragma unroll
  for (int e = 0; e < NEXP; e++)
    for (int d = tid; d < DIM; d += 256)
      wgT[e * DIM + d] = Wg[d * NEXP + e];
  __syncthreads();

  int lane = tid & 63;
  int wv = tid >> 6;
  int b0 = blockIdx.x * GATE_TOK;

  for (int t = 0; t < 16; t++) {
    int lt = wv * 16 + t;
    int b = b0 + lt;
    const float4* zr4 = (const float4*)(z + (size_t)b * DIM);
    float4 zv[4];
#pragma unroll
    for (int i = 0; i < 4; i++) zv[i] = zr4[lane + 64 * i];
    ushort4* zb4 = (ushort4*)((ushort*)zbf + (size_t)b * DIM);
#pragma unroll
    for (int i = 0; i < 4; i++) {
      ushort4 u;
      u.x = f2bf(zv[i].x); u.y = f2bf(zv[i].y);
      u.z = f2bf(zv[i].z); u.w = f2bf(zv[i].w);
      zb4[lane + 64 * i] = u;
    }
    float acc[NEXP];
#pragma unroll
    for (int e = 0; e < NEXP; e++) acc[e] = 0.f;
#pragma unroll
    for (int e = 0; e < NEXP; e++) {
      const float4* wg4 = (const float4*)(wgT + e * DIM);
#pragma unroll
      for (int i = 0; i < 4; i++) {
        float4 w4 = wg4[lane + 64 * i];
        acc[e] += zv[i].x * w4.x + zv[i].y * w4.y + zv[i].z * w4.z + zv[i].w * w4.w;
      }
    }
#pragma unroll
    for (int off = 32; off > 0; off >>= 1) {
#pragma unroll
      for (int e = 0; e < NEXP; e++) acc[e] += __shfl_down(acc[e], off);
    }
    if (lane == 0) {
      float mx = -1e30f;
#pragma unroll
      for (int e = 0; e < NEXP; e++) { acc[e] += bg[e]; mx = fmaxf(mx, acc[e]); }
      float s = 0.f;
#pragma unroll
      for (int e = 0; e < NEXP; e++) { acc[e] = expf(acc[e] - mx); s += acc[e]; }
      float inv = 1.f / s;
      int i1 = -1, i2 = -1; float v1 = -1.f, v2 = -1.f;
#pragma unroll
      for (int e = 0; e < NEXP; e++) {   // stable: first index wins ties (lax.top_k)
        float w = acc[e] * inv;
        if (w > v1) { v2 = v1; i2 = i1; v1 = w; i1 = e; }
        else if (w > v2) { v2 = w; i2 = e; }
      }
      le[2 * lt] = i1;     lw[2 * lt] = v1;
      le[2 * lt + 1] = i2; lw[2 * lt + 1] = v2;
    }
  }
  __syncthreads();
  if (tid < 2 * GATE_TOK) lr[tid] = atomicAdd(&lcnt[le[tid]], 1);
  __syncthreads();
  if (tid < NEXP) gbase[tid] = atomicAdd(&counts[tid], lcnt[tid]);
  __syncthreads();
  if (tid < 2 * GATE_TOK) {
    int e = le[tid];
    int p = gbase[e] + lr[tid];
    int b = b0 + (tid >> 1);
    tokb[e * BTOK + p] = b;
    tokw[e * BTOK + p] = lw[tid];
  }
}

// base[0..7]=token prefix; base[8..16]=gemm1 tile prefix (mt*32, BN=128 over N=4096);
// base[17..25]=gemm2 tile prefix (mt*8, BN=128 over N=1024).  mt = ceil(cnt/128).
__global__ void k_base(const int* __restrict__ counts, int* __restrict__ base) {
  if (threadIdx.x == 0 && blockIdx.x == 0) {
    int s = 0;
    for (int e = 0; e < NEXP; e++) { base[e] = s; s += counts[e]; }
    int a = 0, b = 0;
    base[8] = 0; base[17] = 0;
    for (int e = 0; e < NEXP; e++) {
      int mt = (counts[e] + 127) >> 7;
      a += mt * 32; b += mt * 8;
      base[9 + e] = a; base[18 + e] = b;
    }
  }
}

// =====================================================================
// r9 core: 128x128 tile, 4 waves (2M x 2N, wave-out 64x64), BK=32,
// ring-3 LDS (48 KB -> 3 blocks/CU, grid 768, 12 waves/CU).
// REORDERED PHASE (the r8 post-mortem fix): stage(t+2) -> vmcnt(8) ->
// barrier -> ds_reads(t) -> MFMA -> barrier.  The vmcnt at phase t now
// waits on tile t, ISSUED AT PHASE t-2 (2-phase lead ~3000 cyc >> L2
// latency) instead of tile t+1 issued one phase earlier (the ~400cyc
// stall every phase that pinned all prior rounds at ~15% MfmaUtil).
// VM8 leaves exactly tiles t+1,t+2 (8 loads) in flight.  WAR: stage at
// phase t overwrites buf[(t-1)%3]; its readers drained (lgkm before
// MFMA) ahead of phase t-1's closing barrier.  Mid-barrier after VM8
// broadcasts per-wave residency before any wave reads tile t.
// Tail: VM4 (tile NT-2), VM0 (tile NT-1).
// Work shape = r8 (best duty): merged halves, full-width hbuf, gemm1
// single dispatch N=4096 (4224 tiles/768 -> 85%), gemm2 single dispatch
// with 2 K-seg atomic units (2112/768 -> 75%).
// Swizzle (verified, 0 conflicts): LDS[r][c]=G[r][c^((r>>1)&3)], read
// chunk pc = quad ^ ((lrow>>1)&3); (r>>1)&3 invariant under r->r+64.
// =====================================================================

#define STG4(nxt_, tt_) do {                                                  \
    gload_lds16(srcA0 + (tt_) * 32, &lds[nxt_][(wv * 16) * 32]);              \
    gload_lds16(srcA1 + (tt_) * 32, &lds[nxt_][(64 + wv * 16) * 32]);         \
    gload_lds16(srcB0 + (tt_) * 32, &lds[nxt_][ABASE + (wv * 16) * 32]);      \
    gload_lds16(srcB1 + (tt_) * 32, &lds[nxt_][ABASE + (64 + wv * 16) * 32]); \
  } while (0)

#define PHR(cur_, STG_, VM_) do {                                            \
    STG_;                                                                    \
    __builtin_amdgcn_sched_barrier(0);                                       \
    VM_;                                                                     \
    __builtin_amdgcn_s_barrier();                                            \
    __builtin_amdgcn_sched_barrier(0);                                       \
    const ushort* Ab_ = &lds[cur_][0];                                       \
    const ushort* Bb_ = &lds[cur_][ABASE];                                   \
    bf16x8 afr_[4], bfr_[4];                                                 \
    _Pragma("unroll")                                                        \
    for (int j_ = 0; j_ < 4; j_++)                                           \
      bfr_[j_] = __builtin_bit_cast(bf16x8,                                  \
          *(const uint4*)(Bb_ + boff + j_ * 512));                           \
    _Pragma("unroll")                                                        \
    for (int i_ = 0; i_ < 4; i_++)                                           \
      afr_[i_] = __builtin_bit_cast(bf16x8,                                  \
          *(const uint4*)(Ab_ + aoff + i_ * 512));                           \
    __builtin_amdgcn_s_setprio(1);                                           \
    _Pragma("unroll")                                                        \
    for (int i_ = 0; i_ < 4; i_++)                                           \
      _Pragma("unroll")                                                      \
      for (int j_ = 0; j_ < 4; j_++)                                         \
        acc[i_][j_] = __builtin_amdgcn_mfma_f32_16x16x32_bf16(               \
            afr_[i_], bfr_[j_], acc[i_][j_], 0, 0, 0);                       \
    __builtin_amdgcn_s_setprio(0);                                           \
    __builtin_amdgcn_sched_barrier(0);                                       \
    __builtin_amdgcn_s_barrier();                                            \
  } while (0)

#define VM8  asm volatile("s_waitcnt vmcnt(8)" ::: "memory")
#define VM4  asm volatile("s_waitcnt vmcnt(4)" ::: "memory")
#define VM0  asm volatile("s_waitcnt vmcnt(0)" ::: "memory")
#define NOP_ (void)0

// ---------------- GEMM1: h = relu(zbf[tok]·W1T + b1), full N=4096 ----------------
__global__ __launch_bounds__(256, 3) void k_gemm1(
    const __hip_bfloat16* __restrict__ zbf, const __hip_bfloat16* __restrict__ w1t,
    const float* __restrict__ b1, const int* __restrict__ counts,
    const int* __restrict__ base, const int* __restrict__ tokb,
    __hip_bfloat16* __restrict__ hbuf,
    const int* __restrict__ tp, int* __restrict__ steal) {
  __shared__ __align__(16) ushort lds[3][(128 + 128) * 32];
  __shared__ int sh_g;

  int tid = threadIdx.x;
  int lane = tid & 63;
  int wv = tid >> 6;       // 0..3
  int wm = wv >> 1;        // 0..1
  int wn = wv & 1;         // 0..1
  int lrow = lane & 15;
  int quad = lane >> 4;
  int pc = quad ^ ((lrow >> 1) & 3);
  int aoff = (wm * 64 + lrow) * 32 + pc * 8;
  int boff = (wn * 64 + lrow) * 32 + pc * 8;
  int srow = wv * 16 + (lane >> 2);          // 0..63
  int sswz = ((lane & 3) ^ ((srow >> 1) & 3)) * 8;

  const ushort* zb = (const ushort*)zbf;
  const ushort* w1 = (const ushort*)w1t;
  const int NT = DIM / 32;  // 32
  int TT = tp[8];

  for (;;) {
    if (tid == 0) sh_g = atomicAdd(steal, 1);
    __syncthreads();
    int g = sh_g;
    if (g >= TT) break;

    int e = 0;
    while (g >= tp[e + 1]) e++;
    int local = g - tp[e];
    int mte = (tp[e + 1] - tp[e]) >> 5;   // # m-tiles
    int nt = local / mte;                 // 0..31
    int mtl = local - nt * mte;
    int m0 = mtl * 128, n0 = nt * 128;    // n0 in [0,4096)
    int cnt = counts[e], gb = base[e];

    int ma = m0 + srow;      if (ma >= cnt) ma = cnt - 1;
    int mb = m0 + 64 + srow; if (mb >= cnt) mb = cnt - 1;
    const ushort* srcA0 = zb + (size_t)tokb[e * BTOK + ma] * DIM + sswz;
    const ushort* srcA1 = zb + (size_t)tokb[e * BTOK + mb] * DIM + sswz;
    const ushort* srcB0 = w1 + (size_t)(e * NHID + n0 + srow) * DIM + sswz;
    const ushort* srcB1 = w1 + (size_t)(e * NHID + n0 + 64 + srow) * DIM + sswz;

    STG4(0, 0);
    STG4(1, 1);

    floatx4 acc[4][4];
#pragma unroll
    for (int i = 0; i < 4; i++)
#pragma unroll
      for (int j = 0; j < 4; j++) { floatx4 zf = {0.f,0.f,0.f,0.f}; acc[i][j] = zf; }

    int cur = 0;
#pragma unroll 1
    for (int t = 0; t < NT - 2; ++t) {
      int nxt = cur + 2; if (nxt >= 3) nxt -= 3;
      PHR(cur, STG4(nxt, t + 2), VM8);
      cur = (cur == 2) ? 0 : cur + 1;
    }
    PHR(cur, NOP_, VM4);
    cur = (cur == 2) ? 0 : cur + 1;
    PHR(cur, NOP_, VM0);

    float bias[4];
#pragma unroll
    for (int j = 0; j < 4; j++)
      bias[j] = b1[e * NHID + n0 + wn * 64 + j * 16 + lrow];
    ushort* hp = (ushort*)hbuf;
#pragma unroll
    for (int i = 0; i < 4; i++) {
      int mloc = wm * 64 + i * 16 + quad * 4;
#pragma unroll
      for (int r = 0; r < 4; r++) {
        int mm = m0 + mloc + r;
        if (mm < cnt) {
          ushort* hr = hp + (size_t)(gb + mm) * NHID;   // full-width rows
#pragma unroll
          for (int j = 0; j < 4; j++) {
            float v = fmaxf(acc[i][j][r] + bias[j], 0.f);
            hr[n0 + wn * 64 + j * 16 + lrow] = f2bf(v);
          }
        }
      }
    }
    __syncthreads();
  }
}

// ---------------- GEMM2: out[tok] += w*(h·W2T + b2), 2 K-segment units ----------------
__global__ __launch_bounds__(256, 3) void k_gemm2(
    const __hip_bfloat16* __restrict__ hbuf, const __hip_bfloat16* __restrict__ w2t,
    const float* __restrict__ b2, const int* __restrict__ counts,
    const int* __restrict__ base, const int* __restrict__ tokb,
    const float* __restrict__ tokw, float* __restrict__ out,
    const int* __restrict__ tp, int* __restrict__ steal) {
  __shared__ __align__(16) ushort lds[3][(128 + 128) * 32];
  __shared__ int sh_g;

  int tid = threadIdx.x;
  int lane = tid & 63;
  int wv = tid >> 6;
  int wm = wv >> 1;
  int wn = wv & 1;
  int lrow = lane & 15;
  int quad = lane >> 4;
  int pc = quad ^ ((lrow >> 1) & 3);
  int aoff = (wm * 64 + lrow) * 32 + pc * 8;
  int boff = (wn * 64 + lrow) * 32 + pc * 8;
  int srow = wv * 16 + (lane >> 2);
  int sswz = ((lane & 3) ^ ((srow >> 1) & 3)) * 8;

  const ushort* hb = (const ushort*)hbuf;
  const ushort* w2 = (const ushort*)w2t;
  const int NT = HHALF / 32;  // 64 phases per K-segment
  int TT = tp[8];             // tiles; units = 2*TT

  for (;;) {
    if (tid == 0) sh_g = atomicAdd(steal, 1);
    __syncthreads();
    int gu = sh_g;
    if (gu >= 2 * TT) break;
    int g = gu >> 1;
    int kseg = gu & 1;

    int e = 0;
    while (g >= tp[e + 1]) e++;
    int local = g - tp[e];
    int mte = (tp[e + 1] - tp[e]) >> 3;   // # m-tiles
    int nt = local / mte;                 // 0..7
    int mtl = local - nt * mte;
    int m0 = mtl * 128, n0 = nt * 128;
    int cnt = counts[e], gb = base[e];

    int ma = m0 + srow;      if (ma >= cnt) ma = cnt - 1;
    int mb = m0 + 64 + srow; if (mb >= cnt) mb = cnt - 1;
    const ushort* srcA0 = hb + (size_t)(gb + ma) * NHID + kseg * HHALF + sswz;
    const ushort* srcA1 = hb + (size_t)(gb + mb) * NHID + kseg * HHALF + sswz;
    const ushort* srcB0 = w2 + (size_t)(e * DIM + n0 + srow) * NHID + kseg * HHALF + sswz;
    const ushort* srcB1 = w2 + (size_t)(e * DIM + n0 + 64 + srow) * NHID + kseg * HHALF + sswz;

    STG4(0, 0);
    STG4(1, 1);

    floatx4 acc[4][4];
#pragma unroll
    for (int i = 0; i < 4; i++)
#pragma unroll
      for (int j = 0; j < 4; j++) { floatx4 zf = {0.f,0.f,0.f,0.f}; acc[i][j] = zf; }

    int cur = 0;
#pragma unroll 1
    for (int t = 0; t < NT - 2; ++t) {
      int nxt = cur + 2; if (nxt >= 3) nxt -= 3;
      PHR(cur, STG4(nxt, t + 2), VM8);
      cur = (cur == 2) ? 0 : cur + 1;
    }
    PHR(cur, NOP_, VM4);
    cur = (cur == 2) ? 0 : cur + 1;
    PHR(cur, NOP_, VM0);

#pragma unroll
    for (int i = 0; i < 4; i++) {
      int mloc = wm * 64 + i * 16 + quad * 4;
#pragma unroll
      for (int r = 0; r < 4; r++) {
        int mm = m0 + mloc + r;
        if (mm < cnt) {
          int tk  = tokb[e * BTOK + mm];
          float w = tokw[e * BTOK + mm];
#pragma unroll
          for (int j = 0; j < 4; j++) {
            int n = n0 + wn * 64 + j * 16 + lrow;
            float v = acc[i][j][r] + (kseg == 0 ? b2[e * DIM + n] : 0.f);
            atomicAdd(&out[(size_t)tk * DIM + n], w * v);
          }
        }
      }
    }
    __syncthreads();
  }
}

extern "C" void kernel_launch(void* const* d_in, const int* in_sizes, int n_in,
                              void* d_out, int out_size, void* d_ws, size_t ws_size,
                              hipStream_t stream) {
  const float* z  = (const float*)d_in[0];
  const float* Wg = (const float*)d_in[1];
  const float* bg = (const float*)d_in[2];
  const float* W1 = (const float*)d_in[3];
  const float* b1 = (const float*)d_in[4];
  const float* W2 = (const float*)d_in[5];
  const float* b2 = (const float*)d_in[6];
  float* out = (float*)d_out;
  char* ws = (char*)d_ws;
  if (ws_size < WS_NEED) return;

  int*   counts = (int*)(ws + O_COUNTS);
  int*   base   = (int*)(ws + O_BASE);
  int*   tokb   = (int*)(ws + O_TOKB);
  float* tokw   = (float*)(ws + O_TOKW);
  __hip_bfloat16* zbf  = (__hip_bfloat16*)(ws + O_ZBF);
  __hip_bfloat16* w1t  = (__hip_bfloat16*)(ws + O_W1T);
  __hip_bfloat16* w2t  = (__hip_bfloat16*)(ws + O_W2T);
  __hip_bfloat16* hbuf = (__hip_bfloat16*)(ws + O_HBUF);

  k_zcnt<<<1, 64, 0, stream>>>(counts);
  k_zout<<<512, 256, 0, stream>>>(out);
  k_transpose<<<dim3(NHID / 32, DIM / 32, NEXP), 256, 0, stream>>>(W1, w1t, DIM, NHID);
  k_transpose<<<dim3(DIM / 32, NHID / 32, NEXP), 256, 0, stream>>>(W2, w2t, NHID, DIM);
  k_gate<<<BTOK / GATE_TOK, 256, 0, stream>>>(z, Wg, bg, counts, tokb, tokw, zbf);
  k_base<<<1, 64, 0, stream>>>(counts, base);
  k_gemm1<<<768, 256, 0, stream>>>(
      zbf, w1t, b1, counts, base, tokb, hbuf, base + 8, counts + 8);
  k_gemm2<<<768, 256, 0, stream>>>(
      hbuf, w2t, b2, counts, base, tokb, tokw, out, base + 17, counts + 9);
}

// Round 10
// 864.334 us; speedup vs baseline: 1.0553x; 1.0553x over previous
//
#include <hip/hip_runtime.h>
#include <hip/hip_bf16.h>
#include <cstdint>
#include <cstddef>

#define BTOK  8192
#define DIM   1024
#define NEXP  8
#define NHID  4096
#define HHALF 2048
#define GATE_TOK 64
#define ABASE (128 * 32)   // ushort offset of B region within one LDS buf

typedef __bf16 bf16x8 __attribute__((ext_vector_type(8)));
typedef float  floatx4 __attribute__((ext_vector_type(4)));

// ---- workspace layout (bytes) ----
#define O_COUNTS 0
#define O_BASE   256
#define O_TOKB   1024
#define O_TOKW   (O_TOKB + (size_t)NEXP*BTOK*4)
#define O_CE     (O_TOKW + (size_t)NEXP*BTOK*4)
#define O_CP     (O_CE + (size_t)2*BTOK*4)
#define O_CW     (O_CP + (size_t)2*BTOK*4)
#define O_ZBF    (O_CW + (size_t)2*BTOK*4)
#define O_W1T    (O_ZBF + (size_t)BTOK*DIM*2)
#define O_W2T    (O_W1T + (size_t)NEXP*DIM*NHID*2)
#define O_HBUF   (O_W2T + (size_t)NEXP*DIM*NHID*2)
#define WS_NEED  (O_HBUF + (size_t)2*BTOK*NHID*2)   // = 285,934,592 (proven available)

__device__ __forceinline__ void gload_lds16(const void* g, void* l) {
  __builtin_amdgcn_global_load_lds(
      (const __attribute__((address_space(1))) void*)g,
      (__attribute__((address_space(3))) void*)l, 16, 0, 0);
}

__device__ __forceinline__ ushort f2bf(float x) {
  return __builtin_bit_cast(ushort, __float2bfloat16(x));
}

// ---------------- zero counters + steal counters ----------------
__global__ void k_zcnt(int* __restrict__ counts) {
  if (threadIdx.x < 12) counts[threadIdx.x] = 0;
}

// ---------------- zero out (gemm2 accumulates atomically) ----------------
__global__ void k_zout(float* __restrict__ out) {
  int i = blockIdx.x * blockDim.x + threadIdx.x;
  float4 z4 = {0.f, 0.f, 0.f, 0.f};
  float4* o = (float4*)out;
  int n = BTOK * DIM / 4;
  for (int j = i; j < n; j += gridDim.x * blockDim.x) o[j] = z4;
}

// ---------------- transpose v2: fp32 [Z][R][C] -> bf16 [Z][C][R] ----------------
// 64x64 tiles; conflict-free LDS (65 pitch); ushort4 vectorized bf16 stores
// (old kernel stored 2 B/lane).  Grid: (C/64, R/64, Z).
__global__ __launch_bounds__(256) void k_transpose(
    const float* __restrict__ src, __hip_bfloat16* __restrict__ dst, int R, int C) {
  __shared__ float tile[64][65];
  int zz = blockIdx.z;
  const float* s = src + (size_t)zz * R * C;
  ushort* d = (ushort*)dst + (size_t)zz * R * C;
  int c0 = blockIdx.x * 64, r0 = blockIdx.y * 64;
  int tx = threadIdx.x & 63, ty = threadIdx.x >> 6;   // 64 x 4
#pragma unroll
  for (int i = ty; i < 64; i += 4)
    tile[i][tx] = s[(size_t)(r0 + i) * C + c0 + tx];
  __syncthreads();
  int txq = threadIdx.x & 15, iy = threadIdx.x >> 4;  // 16 x 16
#pragma unroll
  for (int i = iy; i < 64; i += 16) {
    ushort4 u;
    u.x = f2bf(tile[4 * txq + 0][i]);
    u.y = f2bf(tile[4 * txq + 1][i]);
    u.z = f2bf(tile[4 * txq + 2][i]);
    u.w = f2bf(tile[4 * txq + 3][i]);
    *(ushort4*)&d[(size_t)(c0 + i) * R + r0 + 4 * txq] = u;
  }
}

// ---------------- gating ----------------
__global__ __launch_bounds__(256) void k_gate(
    const float* __restrict__ z, const float* __restrict__ Wg,
    const float* __restrict__ bg, int* __restrict__ counts,
    int* __restrict__ tokb, float* __restrict__ tokw,
    __hip_bfloat16* __restrict__ zbf) {
  __shared__ float wgT[NEXP * DIM];       // [e][d]
  __shared__ int   le[2 * GATE_TOK];
  __shared__ float lw[2 * GATE_TOK];
  __shared__ int   lr[2 * GATE_TOK];
  __shared__ int   lcnt[NEXP];
  __shared__ int   gbase[NEXP];

  int tid = threadIdx.x;
  if (tid < NEXP) lcnt[tid] = 0;
#pragma unroll
  for (int e = 0; e < NEXP; e++)
    for (int d = tid; d < DIM; d += 256)
      wgT[e * DIM + d] = Wg[d * NEXP + e];
  __syncthreads();

  int lane = tid & 63;
  int wv = tid >> 6;
  int b0 = blockIdx.x * GATE_TOK;

  for (int t = 0; t < 16; t++) {
    int lt = wv * 16 + t;
    int b = b0 + lt;
    const float4* zr4 = (const float4*)(z + (size_t)b * DIM);
    float4 zv[4];
#pragma unroll
    for (int i = 0; i < 4; i++) zv[i] = zr4[lane + 64 * i];
    ushort4* zb4 = (ushort4*)((ushort*)zbf + (size_t)b * DIM);
#pragma unroll
    for (int i = 0; i < 4; i++) {
      ushort4 u;
      u.x = f2bf(zv[i].x); u.y = f2bf(zv[i].y);
      u.z = f2bf(zv[i].z); u.w = f2bf(zv[i].w);
      zb4[lane + 64 * i] = u;
    }
    float acc[NEXP];
#pragma unroll
    for (int e = 0; e < NEXP; e++) acc[e] = 0.f;
#pragma unroll
    for (int e = 0; e < NEXP; e++) {
      const float4* wg4 = (const float4*)(wgT + e * DIM);
#pragma unroll
      for (int i = 0; i < 4; i++) {
        float4 w4 = wg4[lane + 64 * i];
        acc[e] += zv[i].x * w4.x + zv[i].y * w4.y + zv[i].z * w4.z + zv[i].w * w4.w;
      }
    }
#pragma unroll
    for (int off = 32; off > 0; off >>= 1) {
#pragma unroll
      for (int e = 0; e < NEXP; e++) acc[e] += __shfl_down(acc[e], off);
    }
    if (lane == 0) {
      float mx = -1e30f;
#pragma unroll
      for (int e = 0; e < NEXP; e++) { acc[e] += bg[e]; mx = fmaxf(mx, acc[e]); }
      float s = 0.f;
#pragma unroll
      for (int e = 0; e < NEXP; e++) { acc[e] = expf(acc[e] - mx); s += acc[e]; }
      float inv = 1.f / s;
      int i1 = -1, i2 = -1; float v1 = -1.f, v2 = -1.f;
#pragma unroll
      for (int e = 0; e < NEXP; e++) {   // stable: first index wins ties (lax.top_k)
        float w = acc[e] * inv;
        if (w > v1) { v2 = v1; i2 = i1; v1 = w; i1 = e; }
        else if (w > v2) { v2 = w; i2 = e; }
      }
      le[2 * lt] = i1;     lw[2 * lt] = v1;
      le[2 * lt + 1] = i2; lw[2 * lt + 1] = v2;
    }
  }
  __syncthreads();
  if (tid < 2 * GATE_TOK) lr[tid] = atomicAdd(&lcnt[le[tid]], 1);
  __syncthreads();
  if (tid < NEXP) gbase[tid] = atomicAdd(&counts[tid], lcnt[tid]);
  __syncthreads();
  if (tid < 2 * GATE_TOK) {
    int e = le[tid];
    int p = gbase[e] + lr[tid];
    int b = b0 + (tid >> 1);
    tokb[e * BTOK + p] = b;
    tokw[e * BTOK + p] = lw[tid];
  }
}

// base[0..7]=token prefix; base[8..16]=gemm1 tile prefix (mt*16, BN=256 over N=4096);
// base[17..25]=gemm2 UNIT prefix (mt*8 = 4 nt x 2 kseg, BN=256 over N=1024).
// mt = ceil(cnt/128).
__global__ void k_base(const int* __restrict__ counts, int* __restrict__ base) {
  if (threadIdx.x == 0 && blockIdx.x == 0) {
    int s = 0;
    for (int e = 0; e < NEXP; e++) { base[e] = s; s += counts[e]; }
    int a = 0, b = 0;
    base[8] = 0; base[17] = 0;
    for (int e = 0; e < NEXP; e++) {
      int mt = (counts[e] + 127) >> 7;
      a += mt * 16; b += mt * 8;
      base[9 + e] = a; base[18 + e] = b;
    }
  }
}

// =====================================================================
// r4/r8-proven core: 128x256 tile, 8 waves (2M x 4N, wave-out 64x64),
// BK=32, ring-3 LDS (72 KB -> 2 blocks/CU), counted VM3, dynamic tile
// stealing, verified XOR swizzle (0 conflicts).
// r10 CHANGE (traffic, not schedule): gemm2 unit order is nt-FASTEST
// (mt = local>>3, kseg = (local&7)>>2, nt = local&3) so the 4 units
// sharing one 0.5 MB A-panel are taken by ~concurrent blocks -> A panel
// served from L2/L3 instead of restreamed from HBM per nt-column
// (r9 measured 565 MB fetch; A restream was ~230 MB of it).
// gemm1 order unchanged (A=zbf 33.5 MB is L3-resident; B-panel shared).
// =====================================================================

#define STG3(nxt_, tt_) do {                                                 \
    gload_lds16(srcA  + (tt_) * 32, &lds[nxt_][(wv * 16) * 32]);             \
    gload_lds16(srcB0 + (tt_) * 32, &lds[nxt_][ABASE + (wv * 16) * 32]);     \
    gload_lds16(srcB1 + (tt_) * 32, &lds[nxt_][ABASE + (128 + wv * 16) * 32]);\
  } while (0)

#define PH3(cur_, STG_, VM_) do {                                            \
    const ushort* Ab_ = &lds[cur_][0];                                       \
    const ushort* Bb_ = &lds[cur_][ABASE];                                   \
    bf16x8 afr_[4], bfr_[4];                                                 \
    _Pragma("unroll")                                                        \
    for (int j_ = 0; j_ < 4; j_++)                                           \
      bfr_[j_] = __builtin_bit_cast(bf16x8,                                  \
          *(const uint4*)(Bb_ + boff + j_ * 512));                           \
    _Pragma("unroll")                                                        \
    for (int i_ = 0; i_ < 4; i_++)                                           \
      afr_[i_] = __builtin_bit_cast(bf16x8,                                  \
          *(const uint4*)(Ab_ + aoff + i_ * 512));                           \
    STG_;                                                                    \
    __builtin_amdgcn_sched_barrier(0);                                       \
    VM_;                                                                     \
    __builtin_amdgcn_s_barrier();                                            \
    __builtin_amdgcn_sched_barrier(0);                                       \
    __builtin_amdgcn_s_setprio(1);                                           \
    _Pragma("unroll")                                                        \
    for (int i_ = 0; i_ < 4; i_++)                                           \
      _Pragma("unroll")                                                      \
      for (int j_ = 0; j_ < 4; j_++)                                         \
        acc[i_][j_] = __builtin_amdgcn_mfma_f32_16x16x32_bf16(               \
            afr_[i_], bfr_[j_], acc[i_][j_], 0, 0, 0);                       \
    __builtin_amdgcn_s_setprio(0);                                           \
    __builtin_amdgcn_sched_barrier(0);                                       \
    __builtin_amdgcn_s_barrier();                                            \
  } while (0)

#define VM3  asm volatile("s_waitcnt vmcnt(3)" ::: "memory")
#define VM0  asm volatile("s_waitcnt vmcnt(0)" ::: "memory")
#define NOP_ (void)0

// ---------------- GEMM1: h = relu(zbf[tok]·W1T + b1), full N=4096 ----------------
__global__ __launch_bounds__(512, 4) void k_gemm1(
    const __hip_bfloat16* __restrict__ zbf, const __hip_bfloat16* __restrict__ w1t,
    const float* __restrict__ b1, const int* __restrict__ counts,
    const int* __restrict__ base, const int* __restrict__ tokb,
    __hip_bfloat16* __restrict__ hbuf,
    const int* __restrict__ tp, int* __restrict__ steal) {
  __shared__ __align__(16) ushort lds[3][(128 + 256) * 32];
  __shared__ int sh_g;

  int tid = threadIdx.x;
  int lane = tid & 63;
  int wv = tid >> 6;       // 0..7
  int wm = wv >> 2;        // 0..1
  int wn = wv & 3;         // 0..3
  int lrow = lane & 15;
  int quad = lane >> 4;
  int pc = quad ^ ((lrow >> 1) & 3);
  int aoff = (wm * 64 + lrow) * 32 + pc * 8;
  int boff = (wn * 64 + lrow) * 32 + pc * 8;
  int srow = wv * 16 + (lane >> 2);
  int sswz = ((lane & 3) ^ ((srow >> 1) & 3)) * 8;

  const ushort* zb = (const ushort*)zbf;
  const ushort* w1 = (const ushort*)w1t;
  const int NT = DIM / 32;  // 32
  int TT = tp[8];

  for (;;) {
    if (tid == 0) sh_g = atomicAdd(steal, 1);
    __syncthreads();
    int g = sh_g;
    if (g >= TT) break;

    int e = 0;
    while (g >= tp[e + 1]) e++;
    int local = g - tp[e];
    int mte = (tp[e + 1] - tp[e]) >> 4;   // # m-tiles
    int nt = local / mte;                 // 0..15
    int mtl = local - nt * mte;
    int m0 = mtl * 128, n0 = nt * 256;    // n0 in [0,4096)
    int cnt = counts[e], gb = base[e];

    int m = m0 + srow; if (m >= cnt) m = cnt - 1;
    const ushort* srcA = zb + (size_t)tokb[e * BTOK + m] * DIM + sswz;
    const ushort* srcB0 = w1 + (size_t)(e * NHID + n0 + srow) * DIM + sswz;
    const ushort* srcB1 = w1 + (size_t)(e * NHID + n0 + 128 + srow) * DIM + sswz;

    STG3(0, 0);
    STG3(1, 1);
    VM3;
    __builtin_amdgcn_s_barrier();

    floatx4 acc[4][4];
#pragma unroll
    for (int i = 0; i < 4; i++)
#pragma unroll
      for (int j = 0; j < 4; j++) { floatx4 zf = {0.f,0.f,0.f,0.f}; acc[i][j] = zf; }

    int cur = 0;
#pragma unroll 1
    for (int t = 0; t < NT - 2; ++t) {
      int nxt = cur + 2; if (nxt >= 3) nxt -= 3;
      PH3(cur, STG3(nxt, t + 2), VM3);
      cur = (cur == 2) ? 0 : cur + 1;
    }
    PH3(cur, NOP_, VM0);
    cur = (cur == 2) ? 0 : cur + 1;
    PH3(cur, NOP_, NOP_);

    float bias[4];
#pragma unroll
    for (int j = 0; j < 4; j++)
      bias[j] = b1[e * NHID + n0 + wn * 64 + j * 16 + lrow];
    ushort* hp = (ushort*)hbuf;
#pragma unroll
    for (int i = 0; i < 4; i++) {
      int mloc = wm * 64 + i * 16 + quad * 4;
#pragma unroll
      for (int r = 0; r < 4; r++) {
        int mm = m0 + mloc + r;
        if (mm < cnt) {
          ushort* hr = hp + (size_t)(gb + mm) * NHID;   // full-width rows
#pragma unroll
          for (int j = 0; j < 4; j++) {
            float v = fmaxf(acc[i][j][r] + bias[j], 0.f);
            hr[n0 + wn * 64 + j * 16 + lrow] = f2bf(v);
          }
        }
      }
    }
    __syncthreads();
  }
}

// ---------------- GEMM2: out[tok] += w*(h·W2T + b2), nt-fastest units ----------------
__global__ __launch_bounds__(512, 4) void k_gemm2(
    const __hip_bfloat16* __restrict__ hbuf, const __hip_bfloat16* __restrict__ w2t,
    const float* __restrict__ b2, const int* __restrict__ counts,
    const int* __restrict__ base, const int* __restrict__ tokb,
    const float* __restrict__ tokw, float* __restrict__ out,
    const int* __restrict__ tp, int* __restrict__ steal) {
  __shared__ __align__(16) ushort lds[3][(128 + 256) * 32];
  __shared__ int sh_g;

  int tid = threadIdx.x;
  int lane = tid & 63;
  int wv = tid >> 6;
  int wm = wv >> 2;
  int wn = wv & 3;
  int lrow = lane & 15;
  int quad = lane >> 4;
  int pc = quad ^ ((lrow >> 1) & 3);
  int aoff = (wm * 64 + lrow) * 32 + pc * 8;
  int boff = (wn * 64 + lrow) * 32 + pc * 8;
  int srow = wv * 16 + (lane >> 2);
  int sswz = ((lane & 3) ^ ((srow >> 1) & 3)) * 8;

  const ushort* hb = (const ushort*)hbuf;
  const ushort* w2 = (const ushort*)w2t;
  const int NT = HHALF / 32;  // 64 phases per K-segment
  int TT = tp[8];             // total units (mt*8 per expert)

  for (;;) {
    if (tid == 0) sh_g = atomicAdd(steal, 1);
    __syncthreads();
    int gu = sh_g;
    if (gu >= TT) break;

    int e = 0;
    while (gu >= tp[e + 1]) e++;
    int local = gu - tp[e];
    int mtl  = local >> 3;        // mt slow
    int sub  = local & 7;
    int kseg = sub >> 2;          // kseg mid
    int nt   = sub & 3;           // nt fastest: 4 consecutive units share A panel
    int m0 = mtl * 128, n0 = nt * 256;
    int cnt = counts[e], gb = base[e];

    int m = m0 + srow; if (m >= cnt) m = cnt - 1;
    const ushort* srcA = hb + (size_t)(gb + m) * NHID + kseg * HHALF + sswz;
    const ushort* srcB0 = w2 + (size_t)(e * DIM + n0 + srow) * NHID + kseg * HHALF + sswz;
    const ushort* srcB1 = w2 + (size_t)(e * DIM + n0 + 128 + srow) * NHID + kseg * HHALF + sswz;

    STG3(0, 0);
    STG3(1, 1);
    VM3;
    __builtin_amdgcn_s_barrier();

    floatx4 acc[4][4];
#pragma unroll
    for (int i = 0; i < 4; i++)
#pragma unroll
      for (int j = 0; j < 4; j++) { floatx4 zf = {0.f,0.f,0.f,0.f}; acc[i][j] = zf; }

    int cur = 0;
#pragma unroll 1
    for (int t = 0; t < NT - 2; ++t) {
      int nxt = cur + 2; if (nxt >= 3) nxt -= 3;
      PH3(cur, STG3(nxt, t + 2), VM3);
      cur = (cur == 2) ? 0 : cur + 1;
    }
    PH3(cur, NOP_, VM0);
    cur = (cur == 2) ? 0 : cur + 1;
    PH3(cur, NOP_, NOP_);

#pragma unroll
    for (int i = 0; i < 4; i++) {
      int mloc = wm * 64 + i * 16 + quad * 4;
#pragma unroll
      for (int r = 0; r < 4; r++) {
        int mm = m0 + mloc + r;
        if (mm < cnt) {
          int tk  = tokb[e * BTOK + mm];
          float w = tokw[e * BTOK + mm];
#pragma unroll
          for (int j = 0; j < 4; j++) {
            int n = n0 + wn * 64 + j * 16 + lrow;
            float v = acc[i][j][r] + (kseg == 0 ? b2[e * DIM + n] : 0.f);
            atomicAdd(&out[(size_t)tk * DIM + n], w * v);
          }
        }
      }
    }
    __syncthreads();
  }
}

extern "C" void kernel_launch(void* const* d_in, const int* in_sizes, int n_in,
                              void* d_out, int out_size, void* d_ws, size_t ws_size,
                              hipStream_t stream) {
  const float* z  = (const float*)d_in[0];
  const float* Wg = (const float*)d_in[1];
  const float* bg = (const float*)d_in[2];
  const float* W1 = (const float*)d_in[3];
  const float* b1 = (const float*)d_in[4];
  const float* W2 = (const float*)d_in[5];
  const float* b2 = (const float*)d_in[6];
  float* out = (float*)d_out;
  char* ws = (char*)d_ws;
  if (ws_size < WS_NEED) return;

  int*   counts = (int*)(ws + O_COUNTS);
  int*   base   = (int*)(ws + O_BASE);
  int*   tokb   = (int*)(ws + O_TOKB);
  float* tokw   = (float*)(ws + O_TOKW);
  __hip_bfloat16* zbf  = (__hip_bfloat16*)(ws + O_ZBF);
  __hip_bfloat16* w1t  = (__hip_bfloat16*)(ws + O_W1T);
  __hip_bfloat16* w2t  = (__hip_bfloat16*)(ws + O_W2T);
  __hip_bfloat16* hbuf = (__hip_bfloat16*)(ws + O_HBUF);

  k_zcnt<<<1, 64, 0, stream>>>(counts);
  k_zout<<<512, 256, 0, stream>>>(out);
  k_transpose<<<dim3(NHID / 64, DIM / 64, NEXP), 256, 0, stream>>>(W1, w1t, DIM, NHID);
  k_transpose<<<dim3(DIM / 64, NHID / 64, NEXP), 256, 0, stream>>>(W2, w2t, NHID, DIM);
  k_gate<<<BTOK / GATE_TOK, 256, 0, stream>>>(z, Wg, bg, counts, tokb, tokw, zbf);
  k_base<<<1, 64, 0, stream>>>(counts, base);
  k_gemm1<<<512, 512, 0, stream>>>(
      zbf, w1t, b1, counts, base, tokb, hbuf, base + 8, counts + 8);
  k_gemm2<<<512, 512, 0, stream>>>(
      hbuf, w2t, b2, counts, base, tokb, tokw, out, base + 17, counts + 9);
}